// Round 6
// baseline (283.367 us; speedup 1.0000x reference)
//
#include <hip/hip_runtime.h>
#include <hip/hip_bf16.h>
#include <hip/hip_cooperative_groups.h>

namespace cg = cooperative_groups;

#define N_NODES 4096
#define IN_F    512
#define HEADS   8
#define DH      64
#define HD      512   // HEADS*DH

typedef __bf16 bf16x8 __attribute__((ext_vector_type(8)));
typedef __bf16 bf16x2 __attribute__((ext_vector_type(2)));
typedef float  f32x4  __attribute__((ext_vector_type(4)));
typedef float  f32x2  __attribute__((ext_vector_type(2)));

__device__ __forceinline__ float bf_lo(unsigned u) { return __uint_as_float(u << 16); }
__device__ __forceinline__ float bf_hi(unsigned u) { return __uint_as_float(u & 0xffff0000u); }

// LDS union: phase1 T[8][72] (1.2KB) | phase2 As+Bs+ts (37376B) | phase3 jlist+el+cnt (18436B)
#define SMEM_BYTES 37504

__global__ __launch_bounds__(256, 2) void fused(const float* __restrict__ X,
                                                const float* __restrict__ adj,
                                                const float* __restrict__ W,
                                                const float* __restrict__ a_dst,
                                                float* __restrict__ out,
                                                __bf16* __restrict__ Wt,
                                                __bf16* __restrict__ mx,
                                                float* __restrict__ et) {
    __shared__ __attribute__((aligned(16))) char smem[SMEM_BYTES];
    cg::grid_group grid = cg::this_grid();
    int b = blockIdx.x, tid = threadIdx.x;

    // ================= phase 1: Wt[h*64+d][f] = bf16(W[h][f][d]) =================
    // block b -> head h=b>>6, f-slab of 8 rows at fs=(b&63)*8
    {
        __bf16 (*T)[72] = (__bf16(*)[72])smem;
        int h = b >> 6, fs = (b & 63) * 8;
        int f = tid >> 5, d2 = (tid & 31) * 2;
        f32x2 w2 = *(const f32x2*)(W + ((size_t)h * IN_F + fs + f) * DH + d2);
        T[f][d2]     = (__bf16)w2[0];
        T[f][d2 + 1] = (__bf16)w2[1];
        __syncthreads();
        int d = tid >> 2, fq = (tid & 3) * 2;
        bf16x2 o = { T[fq][d], T[fq + 1][d] };
        *(bf16x2*)(Wt + ((size_t)h * DH + d) * IN_F + fs + fq) = o;
    }
    grid.sync();

    // ================= phase 2: GEMM mx = Xbf16 @ Wt^T  + et epilogue =================
    {
        __bf16* As = (__bf16*)smem;               // [2][64][72]
        __bf16* Bs = (__bf16*)(smem + 18432);     // [2][64][72]
        float*  ts = (float*)(smem + 36864);      // [2][64]
        int h = b & 7, y = b >> 3;                // h = b%8 -> XCD-pinned per head
        int row0 = y * 64, col0 = h * 64;
        int wave = tid >> 6, lane = tid & 63;
        int wm = wave >> 1, wn = wave & 1;
        int lr = lane & 15, kg = lane >> 4;

        f32x4 acc[2][2] = {};

        int sr = tid >> 3, sc = (tid & 7) * 8;
        const float*  aptr0 = X  + (size_t)(row0 + sr) * IN_F + sc;
        const float*  aptr1 = aptr0 + (size_t)32 * IN_F;
        const __bf16* bptr0 = Wt + (size_t)(col0 + sr) * IN_F + sc;
        const __bf16* bptr1 = bptr0 + (size_t)32 * IN_F;

        f32x4 pa00 = *(const f32x4*)aptr0, pa01 = *(const f32x4*)(aptr0 + 4);
        f32x4 pa10 = *(const f32x4*)aptr1, pa11 = *(const f32x4*)(aptr1 + 4);
        uint4 pb0  = *(const uint4*)bptr0, pb1  = *(const uint4*)bptr1;

        float ad0 = a_dst[h * DH + wn * 32 + lr];
        float ad1 = a_dst[h * DH + wn * 32 + 16 + lr];

        #pragma unroll
        for (int k = 0; k < IN_F / 64; ++k) {
            int cur = k & 1;
            bf16x8 a0 = { (__bf16)pa00[0], (__bf16)pa00[1], (__bf16)pa00[2], (__bf16)pa00[3],
                          (__bf16)pa01[0], (__bf16)pa01[1], (__bf16)pa01[2], (__bf16)pa01[3] };
            bf16x8 a1 = { (__bf16)pa10[0], (__bf16)pa10[1], (__bf16)pa10[2], (__bf16)pa10[3],
                          (__bf16)pa11[0], (__bf16)pa11[1], (__bf16)pa11[2], (__bf16)pa11[3] };
            *(bf16x8*)&As[(cur * 64 + sr) * 72 + sc]      = a0;
            *(bf16x8*)&As[(cur * 64 + sr + 32) * 72 + sc] = a1;
            *(uint4*)&Bs[(cur * 64 + sr) * 72 + sc]       = pb0;
            *(uint4*)&Bs[(cur * 64 + sr + 32) * 72 + sc]  = pb1;
            if (k + 1 < IN_F / 64) {
                int off = (k + 1) * 64;
                pa00 = *(const f32x4*)(aptr0 + off); pa01 = *(const f32x4*)(aptr0 + off + 4);
                pa10 = *(const f32x4*)(aptr1 + off); pa11 = *(const f32x4*)(aptr1 + off + 4);
                pb0  = *(const uint4*)(bptr0 + off); pb1  = *(const uint4*)(bptr1 + off);
            }
            __syncthreads();
            #pragma unroll
            for (int kc = 0; kc < 2; ++kc) {
                bf16x8 af0 = *(const bf16x8*)&As[(cur * 64 + wm * 32 + lr) * 72      + kc * 32 + kg * 8];
                bf16x8 af1 = *(const bf16x8*)&As[(cur * 64 + wm * 32 + 16 + lr) * 72 + kc * 32 + kg * 8];
                bf16x8 bf0 = *(const bf16x8*)&Bs[(cur * 64 + wn * 32 + lr) * 72      + kc * 32 + kg * 8];
                bf16x8 bf1 = *(const bf16x8*)&Bs[(cur * 64 + wn * 32 + 16 + lr) * 72 + kc * 32 + kg * 8];
                acc[0][0] = __builtin_amdgcn_mfma_f32_16x16x32_bf16(af0, bf0, acc[0][0], 0, 0, 0);
                acc[0][1] = __builtin_amdgcn_mfma_f32_16x16x32_bf16(af0, bf1, acc[0][1], 0, 0, 0);
                acc[1][0] = __builtin_amdgcn_mfma_f32_16x16x32_bf16(af1, bf0, acc[1][0], 0, 0, 0);
                acc[1][1] = __builtin_amdgcn_mfma_f32_16x16x32_bf16(af1, bf1, acc[1][1], 0, 0, 0);
            }
            // single barrier/iter: buffer written at k+1 was last read at k-1 (barrier k between)
        }

        // epilogue 1: mx store.  C/D layout: col=lane&15, row=(lane>>4)*4+reg
        #pragma unroll
        for (int mt = 0; mt < 2; ++mt) {
            #pragma unroll
            for (int nt = 0; nt < 2; ++nt) {
                int col = col0 + wn * 32 + nt * 16 + lr;
                #pragma unroll
                for (int r4 = 0; r4 < 4; ++r4) {
                    int row = row0 + wm * 32 + mt * 16 + kg * 4 + r4;
                    mx[(size_t)row * HD + col] = (__bf16)acc[mt][nt][r4];
                }
            }
        }
        // epilogue 2: et[row][h] = exp(sum_d acc*a_dst) from pre-rounding fp32 acc
        #pragma unroll
        for (int mt = 0; mt < 2; ++mt) {
            #pragma unroll
            for (int r4 = 0; r4 < 4; ++r4) {
                float p = ad0 * acc[mt][0][r4] + ad1 * acc[mt][1][r4];
                p += __shfl_xor(p, 1);
                p += __shfl_xor(p, 2);
                p += __shfl_xor(p, 4);
                p += __shfl_xor(p, 8);
                if (lr == 0) ts[wn * 64 + wm * 32 + mt * 16 + kg * 4 + r4] = p;
            }
        }
        __syncthreads();
        if (tid < 64) {
            float t = ts[tid] + ts[64 + tid];
            et[(size_t)(row0 + tid) * HEADS + h] = __expf(t);
        }
    }
    grid.sync();

    // ================= phase 3: per-row neighbor scan + softmax aggregation =================
    // block b handles rows b*8 .. b*8+7; next row's adj prefetched into regs during phase B.
    {
        int*   jlist = (int*)smem;                    // 512 ints
        float* el    = (float*)(smem + 2048);         // 4096 floats
        int*   cntp  = (int*)(smem + 2048 + 16384);
        const unsigned* mxu = (const unsigned*)mx;    // 256 uints per row
        int h3 = tid >> 5;
        int base_i = b * 8;
        int j0 = tid * 16;

        uint4 q0, q1, q2, q3;
        {
            const float* arow = adj + (size_t)base_i * N_NODES + j0;
            q0 = *(const uint4*)arow;        q1 = *(const uint4*)(arow + 4);
            q2 = *(const uint4*)(arow + 8);  q3 = *(const uint4*)(arow + 12);
        }
        for (int r = 0; r < 8; ++r) {
            int i = base_i + r;
            if (tid == 0) *cntp = 0;
            __syncthreads();
            unsigned vv[16] = { q0.x, q0.y, q0.z, q0.w, q1.x, q1.y, q1.z, q1.w,
                                q2.x, q2.y, q2.z, q2.w, q3.x, q3.y, q3.z, q3.w };
            #pragma unroll
            for (int q = 0; q < 16; ++q)
                if (vv[q]) { int s = atomicAdd(cntp, 1); if (s < 512) jlist[s] = j0 + q; }
            __syncthreads();
            int c = *cntp; if (c > 512) c = 512;
            for (int idx = tid; idx < c * 8; idx += 256)
                el[idx] = et[(size_t)jlist[idx >> 3] * 8 + (idx & 7)];
            if (r < 7) {   // prefetch next row's adj; consumed next iter (overlaps phase B)
                const float* arow = adj + (size_t)(i + 1) * N_NODES + j0;
                q0 = *(const uint4*)arow;        q1 = *(const uint4*)(arow + 4);
                q2 = *(const uint4*)(arow + 8);  q3 = *(const uint4*)(arow + 12);
            }
            __syncthreads();
            // phase B: thread owns cols (2tid, 2tid+1), head h3; one 4B load per neighbor
            float a0 = 0.f, a1 = 0.f, d = 0.f;
            int k = 0;
            for (; k + 4 <= c; k += 4) {
                int j0_ = jlist[k], j1_ = jlist[k + 1], j2_ = jlist[k + 2], j3_ = jlist[k + 3];
                float e0 = el[(k    ) * 8 + h3], e1 = el[(k + 1) * 8 + h3];
                float e2 = el[(k + 2) * 8 + h3], e3 = el[(k + 3) * 8 + h3];
                unsigned p0 = mxu[(size_t)j0_ * 256 + tid];
                unsigned p1 = mxu[(size_t)j1_ * 256 + tid];
                unsigned p2 = mxu[(size_t)j2_ * 256 + tid];
                unsigned p3 = mxu[(size_t)j3_ * 256 + tid];
                a0 += e0 * bf_lo(p0) + e1 * bf_lo(p1) + e2 * bf_lo(p2) + e3 * bf_lo(p3);
                a1 += e0 * bf_hi(p0) + e1 * bf_hi(p1) + e2 * bf_hi(p2) + e3 * bf_hi(p3);
                d  += e0 + e1 + e2 + e3;
            }
            for (; k < c; ++k) {
                int j = jlist[k];
                float e = el[k * 8 + h3];
                unsigned p = mxu[(size_t)j * 256 + tid];
                a0 += e * bf_lo(p);
                a1 += e * bf_hi(p);
                d  += e;
            }
            float inv = 1.f / d;
            out[(size_t)i * HD + tid * 2]     = a0 * inv;
            out[(size_t)i * HD + tid * 2 + 1] = a1 * inv;
        }
    }
}

extern "C" void kernel_launch(void* const* d_in, const int* in_sizes, int n_in,
                              void* d_out, int out_size, void* d_ws, size_t ws_size,
                              hipStream_t stream) {
    const float* x     = (const float*)d_in[0];
    const float* adj   = (const float*)d_in[1];
    const float* W     = (const float*)d_in[2];
    // d_in[3] = a_origin: dead (softmax shift invariance over j)
    const float* a_dst = (const float*)d_in[4];
    float* out = (float*)d_out;

    char* ws = (char*)d_ws;
    __bf16* Wt = (__bf16*)ws;                     // 512 KB  [512][512]
    __bf16* mx = (__bf16*)(ws + 524288);          // 4 MB    [4096][512]
    float*  et = (float*)(ws + 4718592);          // 128 KB  [4096][8]

    void* args[] = { (void*)&x, (void*)&adj, (void*)&W, (void*)&a_dst,
                     (void*)&out, (void*)&Wt, (void*)&mx, (void*)&et };
    hipLaunchCooperativeKernel((void*)fused, dim3(512), dim3(256), args, 0, stream);
}

// Round 7
// 133.309 us; speedup vs baseline: 2.1256x; 2.1256x over previous
//
#include <hip/hip_runtime.h>
#include <hip/hip_bf16.h>

#define N_NODES 4096
#define IN_F    512
#define HEADS   8
#define DH      64
#define HD      512   // HEADS*DH

typedef __bf16 bf16x8 __attribute__((ext_vector_type(8)));
typedef float  f32x4  __attribute__((ext_vector_type(4)));

__device__ __forceinline__ float bf_lo(unsigned u) { return __uint_as_float(u << 16); }
__device__ __forceinline__ float bf_hi(unsigned u) { return __uint_as_float(u & 0xffff0000u); }

// ---------------- Kernel 1: GEMM  mx[n][h*64+d] = sum_f X[n][f] * W[h][f][d]
// Self-contained: A (X fp32) cvt->bf16 inline; B (W fp32) transposed in-staging
// (W[h] = 128 KB, XCD-L2-resident since h = blockIdx.x&7 pins heads to XCDs).
// + fused et epilogue: et[n][h] = exp( sum_d acc_fp32[n][d] * a_dst[h][d] ).
// BM=BN=BK=64, 512 blocks (2/CU), register-prefetch + dbuf LDS, 1 barrier/iter.
#define KP 72   // 144 B rows: 16B-aligned for ds_*_b128

__global__ __launch_bounds__(256, 2) void k1_gemm(const float* __restrict__ X,
                                                  const float* __restrict__ W,
                                                  const float* __restrict__ a_dst,
                                                  __bf16* __restrict__ C,
                                                  float* __restrict__ et) {
    __shared__ __bf16 As[2][64][KP];
    __shared__ __bf16 Bs[2][64][KP];
    __shared__ float  ts[2][64];
    int tid  = threadIdx.x;
    int h    = blockIdx.x & 7;     // head round-robins the 8 XCDs
    int y    = blockIdx.x >> 3;
    int row0 = y * 64, col0 = h * 64;
    int wave = tid >> 6, lane = tid & 63;
    int wm = wave >> 1, wn = wave & 1;
    int lr = lane & 15, kg = lane >> 4;

    f32x4 acc[2][2] = {};

    // A staging: thread -> rows (sr, sr+32), 8 cols at sc
    int sr = tid >> 3, sc = (tid & 7) * 8;
    const float* aptr0 = X + (size_t)(row0 + sr) * IN_F + sc;
    const float* aptr1 = aptr0 + (size_t)32 * IN_F;
    // B staging (transposing): thread -> col d, 16 f-rows at fq
    int dcol = tid & 63, fq = (tid >> 6) * 16;
    const float* wptr = W + ((size_t)h * IN_F + fq) * DH + dcol;

    f32x4 pa00 = *(const f32x4*)aptr0, pa01 = *(const f32x4*)(aptr0 + 4);
    f32x4 pa10 = *(const f32x4*)aptr1, pa11 = *(const f32x4*)(aptr1 + 4);
    float wv[16];
    #pragma unroll
    for (int i = 0; i < 16; ++i) wv[i] = wptr[(size_t)i * DH];

    float ad0 = a_dst[h * DH + wn * 32 + lr];
    float ad1 = a_dst[h * DH + wn * 32 + 16 + lr];

    #pragma unroll
    for (int k = 0; k < IN_F / 64; ++k) {
        int cur = k & 1;
        bf16x8 a0 = { (__bf16)pa00[0], (__bf16)pa00[1], (__bf16)pa00[2], (__bf16)pa00[3],
                      (__bf16)pa01[0], (__bf16)pa01[1], (__bf16)pa01[2], (__bf16)pa01[3] };
        bf16x8 a1 = { (__bf16)pa10[0], (__bf16)pa10[1], (__bf16)pa10[2], (__bf16)pa10[3],
                      (__bf16)pa11[0], (__bf16)pa11[1], (__bf16)pa11[2], (__bf16)pa11[3] };
        bf16x8 b0 = { (__bf16)wv[0],  (__bf16)wv[1],  (__bf16)wv[2],  (__bf16)wv[3],
                      (__bf16)wv[4],  (__bf16)wv[5],  (__bf16)wv[6],  (__bf16)wv[7] };
        bf16x8 b1 = { (__bf16)wv[8],  (__bf16)wv[9],  (__bf16)wv[10], (__bf16)wv[11],
                      (__bf16)wv[12], (__bf16)wv[13], (__bf16)wv[14], (__bf16)wv[15] };
        *(bf16x8*)&As[cur][sr][sc]        = a0;
        *(bf16x8*)&As[cur][sr + 32][sc]   = a1;
        *(bf16x8*)&Bs[cur][dcol][fq]      = b0;   // Bs[d][f] = W^T : transpose done here
        *(bf16x8*)&Bs[cur][dcol][fq + 8]  = b1;
        if (k + 1 < IN_F / 64) {
            int off = (k + 1) * 64;
            pa00 = *(const f32x4*)(aptr0 + off); pa01 = *(const f32x4*)(aptr0 + off + 4);
            pa10 = *(const f32x4*)(aptr1 + off); pa11 = *(const f32x4*)(aptr1 + off + 4);
            const float* wp = wptr + (size_t)off * DH;
            #pragma unroll
            for (int i = 0; i < 16; ++i) wv[i] = wp[(size_t)i * DH];
        }
        __syncthreads();
        #pragma unroll
        for (int kc = 0; kc < 2; ++kc) {
            bf16x8 af0 = *(const bf16x8*)&As[cur][wm * 32 + lr]     [kc * 32 + kg * 8];
            bf16x8 af1 = *(const bf16x8*)&As[cur][wm * 32 + 16 + lr][kc * 32 + kg * 8];
            bf16x8 bf0 = *(const bf16x8*)&Bs[cur][wn * 32 + lr]     [kc * 32 + kg * 8];
            bf16x8 bf1 = *(const bf16x8*)&Bs[cur][wn * 32 + 16 + lr][kc * 32 + kg * 8];
            acc[0][0] = __builtin_amdgcn_mfma_f32_16x16x32_bf16(af0, bf0, acc[0][0], 0, 0, 0);
            acc[0][1] = __builtin_amdgcn_mfma_f32_16x16x32_bf16(af0, bf1, acc[0][1], 0, 0, 0);
            acc[1][0] = __builtin_amdgcn_mfma_f32_16x16x32_bf16(af1, bf0, acc[1][0], 0, 0, 0);
            acc[1][1] = __builtin_amdgcn_mfma_f32_16x16x32_bf16(af1, bf1, acc[1][1], 0, 0, 0);
        }
        // single barrier/iter: buffer written at k+1 was last read at k-1 (barrier k between)
    }

    // epilogue 1: mx store.  C/D layout: col=lane&15, row=(lane>>4)*4+reg
    #pragma unroll
    for (int mt = 0; mt < 2; ++mt) {
        #pragma unroll
        for (int nt = 0; nt < 2; ++nt) {
            int col = col0 + wn * 32 + nt * 16 + lr;
            #pragma unroll
            for (int r = 0; r < 4; ++r) {
                int row = row0 + wm * 32 + mt * 16 + kg * 4 + r;
                C[(size_t)row * HD + col] = (__bf16)acc[mt][nt][r];
            }
        }
    }
    // epilogue 2: et[row][h] = exp(sum_d acc*a_dst) from pre-rounding fp32 acc
    #pragma unroll
    for (int mt = 0; mt < 2; ++mt) {
        #pragma unroll
        for (int r = 0; r < 4; ++r) {
            float p = ad0 * acc[mt][0][r] + ad1 * acc[mt][1][r];
            p += __shfl_xor(p, 1);
            p += __shfl_xor(p, 2);
            p += __shfl_xor(p, 4);
            p += __shfl_xor(p, 8);
            if (lr == 0) ts[wn][wm * 32 + mt * 16 + kg * 4 + r] = p;
        }
    }
    __syncthreads();
    if (tid < 64) {
        float t = ts[0][tid] + ts[1][tid];
        et[(size_t)(row0 + tid) * HEADS + h] = __expf(t);
    }
}

// ---------------- Kernel 3: per row i — neighbor scan + softmax-weighted aggregation
#define MAXNBR 512
__global__ __launch_bounds__(256) void k3_aggr(const float* __restrict__ adj,
                                               const __bf16* __restrict__ mx,
                                               const float* __restrict__ et,
                                               float* __restrict__ out) {
    __shared__ int   jlist[MAXNBR];
    __shared__ float el[MAXNBR * 8];
    __shared__ int   cnt;
    int tid = threadIdx.x;
    int i   = blockIdx.x;
    if (tid == 0) cnt = 0;
    __syncthreads();

    // phase A: scan adj row (16 KB coalesced), push nonzero j
    {
        const float* arow = adj + (size_t)i * N_NODES;
        int j0 = tid * 16;
        #pragma unroll
        for (int q = 0; q < 4; ++q) {
            uint4 p = *(const uint4*)(arow + j0 + q * 4);
            int jb = j0 + q * 4;
            if (p.x) { int s = atomicAdd(&cnt, 1); if (s < MAXNBR) jlist[s] = jb;     }
            if (p.y) { int s = atomicAdd(&cnt, 1); if (s < MAXNBR) jlist[s] = jb + 1; }
            if (p.z) { int s = atomicAdd(&cnt, 1); if (s < MAXNBR) jlist[s] = jb + 2; }
            if (p.w) { int s = atomicAdd(&cnt, 1); if (s < MAXNBR) jlist[s] = jb + 3; }
        }
    }
    __syncthreads();
    int c = cnt < MAXNBR ? cnt : MAXNBR;

    // phase A2: gather exp(t) for neighbors, all heads
    for (int idx = tid; idx < c * 8; idx += 256)
        el[idx] = et[(size_t)jlist[idx >> 3] * 8 + (idx & 7)];
    __syncthreads();

    // phase B: thread owns 2 adjacent cols (2tid, 2tid+1), head h = tid>>5; one 4B load/j.
    int h = tid >> 5;
    const unsigned* mxu = (const unsigned*)mx;   // 256 uints per row
    float a0 = 0.f, a1 = 0.f, d = 0.f;
    int k = 0;
    for (; k + 4 <= c; k += 4) {
        int j0_ = jlist[k], j1_ = jlist[k+1], j2_ = jlist[k+2], j3_ = jlist[k+3];
        float e0 = el[(k    ) * 8 + h], e1 = el[(k + 1) * 8 + h];
        float e2 = el[(k + 2) * 8 + h], e3 = el[(k + 3) * 8 + h];
        unsigned p0 = mxu[(size_t)j0_ * 256 + tid];
        unsigned p1 = mxu[(size_t)j1_ * 256 + tid];
        unsigned p2 = mxu[(size_t)j2_ * 256 + tid];
        unsigned p3 = mxu[(size_t)j3_ * 256 + tid];
        a0 += e0 * bf_lo(p0) + e1 * bf_lo(p1) + e2 * bf_lo(p2) + e3 * bf_lo(p3);
        a1 += e0 * bf_hi(p0) + e1 * bf_hi(p1) + e2 * bf_hi(p2) + e3 * bf_hi(p3);
        d  += e0 + e1 + e2 + e3;
    }
    for (; k < c; ++k) {
        int j = jlist[k];
        float e = el[k * 8 + h];
        unsigned p = mxu[(size_t)j * 256 + tid];
        a0 += e * bf_lo(p);
        a1 += e * bf_hi(p);
        d  += e;
    }
    float inv = 1.f / d;
    out[(size_t)i * HD + tid * 2]     = a0 * inv;
    out[(size_t)i * HD + tid * 2 + 1] = a1 * inv;
}

extern "C" void kernel_launch(void* const* d_in, const int* in_sizes, int n_in,
                              void* d_out, int out_size, void* d_ws, size_t ws_size,
                              hipStream_t stream) {
    const float* x     = (const float*)d_in[0];
    const float* adj   = (const float*)d_in[1];
    const float* W     = (const float*)d_in[2];
    // d_in[3] = a_origin: dead (softmax shift invariance over j)
    const float* a_dst = (const float*)d_in[4];
    float* out = (float*)d_out;

    char* ws = (char*)d_ws;
    __bf16* mx = (__bf16*)ws;                     // 4 MB    [4096][512]
    float*  et = (float*)(ws + 4194304);          // 128 KB  [4096][8]

    k1_gemm<<<dim3(512), dim3(256), 0, stream>>>(x, W, a_dst, mx, et);
    k3_aggr<<<dim3(N_NODES), dim3(256), 0, stream>>>(adj, mx, et, out);
}